// Round 13
// baseline (288.935 us; speedup 1.0000x reference)
//
#include <hip/hip_runtime.h>

#define NH 8
#define CDIM 384
#define HDIM 48
#define NTOK 4096
#define PDIM 256
#define BDIM 4

typedef unsigned short u16;
typedef unsigned int u32;
typedef __bf16 bf16x8 __attribute__((ext_vector_type(8)));
typedef float f32x4 __attribute__((ext_vector_type(4)));

__device__ __forceinline__ u16 f2b(float f) {
    u32 u = __float_as_uint(f);
    u = (u + 0x7fffu + ((u >> 16) & 1u)) >> 16;   // RNE bf16
    return (u16)u;
}
__device__ __forceinline__ float b2f(u16 u) {
    return __uint_as_float(((u32)u) << 16);
}

__device__ __forceinline__ bf16x8 bzero8() {
    bf16x8 v;
#pragma unroll
    for (int i = 0; i < 8; i++) v[i] = (__bf16)0.0f;
    return v;
}

__device__ __forceinline__ void gload16(const u16* g, u16* l) {
    __builtin_amdgcn_global_load_lds(
        (const __attribute__((address_space(1))) void*)g,
        (__attribute__((address_space(3))) void*)l, 16, 0, 0);
}

// tanh-form GELU, max abs err ~3e-4 vs exact erf form
__device__ __forceinline__ float gelu_f(float x) {
    float z = 0.7978845608028654f * (x + 0.044715f * x * x * x);
    float e = __expf(2.0f * z);
    float t = 1.0f - 2.0f / (e + 1.0f);
    return 0.5f * x * (1.0f + t);
}

// ---------------------------------------------------------------------------
// Unified multi-transpose: ALL f32->bf16 transposes in ONE launch.
// desc i: src f32 [nz, R, C] -> dT bf16 [nz, C, R]; optional dC bf16 [nz,R,C].
// 32x32 tiles, block (32,8). Flat 1-D grid over all descs' tiles.
// ---------------------------------------------------------------------------
#define NDESC 6
struct TDesc {
    const float* src; u16* dT; u16* dC;
    int R, C, ntx, nty, start;   // start = first flat tile id of this desc
};
struct TDescs { TDesc d[NDESC]; };

__global__ __launch_bounds__(256) void multi_transpose(TDescs td)
{
    __shared__ float tile[32][33];
    int t = blockIdx.x;
    int di = 0;
#pragma unroll
    for (int i = 1; i < NDESC; i++) if (t >= td.d[i].start) di = i;
    const TDesc& D = td.d[di];
    int lt = t - D.start;
    int perZ = D.ntx * D.nty;
    int z = lt / perZ;
    int rr = lt % perZ;
    int r0 = (rr / D.ntx) * 32, c0 = (rr % D.ntx) * 32;
    size_t zoff = (size_t)z * D.R * D.C;
    const float* inp = D.src + zoff;
    int tx = threadIdx.x, ty = threadIdx.y;
#pragma unroll
    for (int i = 0; i < 4; i++) {
        int r = r0 + ty + i * 8;
        float v = inp[(size_t)r * D.C + c0 + tx];
        tile[ty + i * 8][tx] = v;
        if (D.dC) D.dC[zoff + (size_t)r * D.C + c0 + tx] = f2b(v);
    }
    __syncthreads();
    u16* oT = D.dT + zoff;
#pragma unroll
    for (int i = 0; i < 4; i++) {
        int c = c0 + ty + i * 8;
        oT[(size_t)c * D.R + r0 + tx] = f2b(tile[tx][ty + i * 8]);
    }
}

// ---------------------------------------------------------------------------
// GEMM: C[M,N] = A[M,K](bf16,row) @ Bt[N,K](bf16,row)^T, f32 accum.
// Tile BMv x BNv, BK=32, 4 waves (2x2), 16x16x32 MFMA.
// 3-deep LDS ring + counted vmcnt; ONE s_barrier per K-step.
// T2 swizzle both-sides (source-chunk permute ch^=(r>>1)&3, same on read).
// SWZ=1: 1-D grid, XCD-chunked remap (T1).
// SWAPC (EPI != 2): swapped operands -> packed float4/ushort4 stores.
// EPI 0: f32 store; EPI 1: gelu->bf16; EPI 2: +bias+Y transposed f32 out;
// EPI 4: split-8 K partials; EPI 5: bf16 store with batch offset.
// ---------------------------------------------------------------------------
template <int EPI, int BMv, int BNv, int SWZ>
__global__ __launch_bounds__(256) void gemm_bt(
    const u16* __restrict__ A, const u16* __restrict__ Bt,
    int M, int Nn, int K, long sA, long sB, long sC, int nBN,
    float* __restrict__ Cf, const float* __restrict__ bias,
    u16* __restrict__ Cbf, const float* __restrict__ Yin, float* __restrict__ Out)
{
    constexpr bool SWAPC = (EPI != 2);
    const int MT = BMv / 32, NT = BNv / 32;
    const int BK = 32, LP = 32;
    __shared__ u16 lsA[3][BMv * LP];
    __shared__ u16 lsB[3][BNv * LP];
    const int tid = threadIdx.x;
    const int wave = tid >> 6, lane = tid & 63;
    const int lm = lane & 15, lkb = lane >> 4;
    int bm, bn;
    const int bz = blockIdx.z;
    if (SWZ) {
        int nwg = gridDim.x;                     // divisible by 8
        int w = ((blockIdx.x & 7) * (nwg >> 3)) + (blockIdx.x >> 3);
        bm = w / nBN; bn = w % nBN;
    } else {
        bm = blockIdx.x; bn = blockIdx.y;
    }
    int bb = bz, ks = 0, ke = K;
    if (EPI == 4) { bb = bz >> 3; ks = (bz & 7) * (K >> 3); ke = ks + (K >> 3); }
    const u16* Ab = A + (size_t)bb * sA;
    const u16* Bb = Bt + (size_t)bb * sB;
    const int wm = (wave >> 1) * (BMv / 2), wn = (wave & 1) * (BNv / 2);

    f32x4 acc[MT][NT];
#pragma unroll
    for (int i = 0; i < MT; i++)
#pragma unroll
        for (int j = 0; j < NT; j++) acc[i][j] = f32x4{0.f, 0.f, 0.f, 0.f};

    // swizzled global source chunk: LDS chunk (r, c) holds global chunk c^((r>>1)&3)
    auto stage = [&](int k0, int c) {
#pragma unroll
        for (int j = 0; j < BMv / 64; j++) {
            int cb = (j * 4 + wave) * 64;
            int q = cb + lane;
            int r = q >> 2, ch = (q & 3) ^ ((r >> 1) & 3);
            gload16(Ab + (size_t)(bm * BMv + r) * K + k0 + ch * 8, &lsA[c][cb * 8]);
        }
#pragma unroll
        for (int j = 0; j < BNv / 64; j++) {
            int cb = (j * 4 + wave) * 64;
            int q = cb + lane;
            int r = q >> 2, ch = (q & 3) ^ ((r >> 1) & 3);
            gload16(Bb + (size_t)(bn * BNv + r) * K + k0 + ch * 8, &lsB[c][cb * 8]);
        }
    };
    // loads per stage per thread
    constexpr int NLD = (BMv + BNv) / 64;
    #define WAIT_LD() do { \
        if constexpr (NLD == 3)      asm volatile("s_waitcnt vmcnt(3)" ::: "memory"); \
        else if constexpr (NLD == 4) asm volatile("s_waitcnt vmcnt(4)" ::: "memory"); \
        else                         asm volatile("s_waitcnt vmcnt(6)" ::: "memory"); \
    } while (0)

    const int nt = (ke - ks) / BK;   // all launches have nt >= 8
    stage(ks, 0);
    stage(ks + BK, 1);
    WAIT_LD();                        // tile 0 complete (tile 1 in flight)
    __builtin_amdgcn_s_barrier();

    for (int t = 0; t < nt; ++t) {
        const int cur = t % 3;
        if (t + 2 < nt) stage(ks + (t + 2) * BK, (t + 2) % 3);
        bf16x8 af[MT], bfr[NT];
#pragma unroll
        for (int m = 0; m < MT; m++) {
            int R = wm + m * 16 + lm;
            af[m] = *(const bf16x8*)&lsA[cur][R * LP + ((lkb ^ ((R >> 1) & 3)) * 8)];
        }
#pragma unroll
        for (int n = 0; n < NT; n++) {
            int R = wn + n * 16 + lm;
            bfr[n] = *(const bf16x8*)&lsB[cur][R * LP + ((lkb ^ ((R >> 1) & 3)) * 8)];
        }
#pragma unroll
        for (int mi = 0; mi < MT; mi++)
#pragma unroll
            for (int ni = 0; ni < NT; ni++) {
                if (SWAPC)
                    acc[mi][ni] = __builtin_amdgcn_mfma_f32_16x16x32_bf16(
                        bfr[ni], af[mi], acc[mi][ni], 0, 0, 0);
                else
                    acc[mi][ni] = __builtin_amdgcn_mfma_f32_16x16x32_bf16(
                        af[mi], bfr[ni], acc[mi][ni], 0, 0, 0);
            }
        if (t + 1 < nt) {
            if (t + 2 < nt) { WAIT_LD(); }
            else { asm volatile("s_waitcnt vmcnt(0)" ::: "memory"); }
            __builtin_amdgcn_s_barrier();
        }
    }
    #undef WAIT_LD

    if (EPI == 2) {
        // unswapped: acc[.][.][r] spans 4 consecutive m (= tok)
#pragma unroll
        for (int mi = 0; mi < MT; mi++)
#pragma unroll
            for (int ni = 0; ni < NT; ni++) {
                int m0 = bm * BMv + wm + mi * 16 + lkb * 4;
                int n = bn * BNv + wn + ni * 16 + lm;
                int b = m0 >> 12, tok = m0 & 4095;
                size_t oi = ((size_t)b * CDIM + n) * NTOK + tok;
                float4 yv = *(const float4*)(Yin + oi);
                float bv = bias[n];
                float4 ov;
                ov.x = acc[mi][ni][0] + bv + yv.x;
                ov.y = acc[mi][ni][1] + bv + yv.y;
                ov.z = acc[mi][ni][2] + bv + yv.z;
                ov.w = acc[mi][ni][3] + bv + yv.w;
                *(float4*)(Out + oi) = ov;
            }
    } else {
        // SWAPC: acc[.][.][r] spans 4 consecutive n
#pragma unroll
        for (int mi = 0; mi < MT; mi++)
#pragma unroll
            for (int ni = 0; ni < NT; ni++) {
                int m = bm * BMv + wm + mi * 16 + lm;
                int n = bn * BNv + wn + ni * 16 + lkb * 4;
                if (EPI == 0 || EPI == 4) {
                    *(float4*)(Cf + (size_t)bz * sC + (size_t)m * Nn + n) =
                        float4{acc[mi][ni][0], acc[mi][ni][1],
                               acc[mi][ni][2], acc[mi][ni][3]};
                } else if (EPI == 1) {
                    ushort4 ov;
                    ov.x = f2b(gelu_f(acc[mi][ni][0] + bias[n + 0]));
                    ov.y = f2b(gelu_f(acc[mi][ni][1] + bias[n + 1]));
                    ov.z = f2b(gelu_f(acc[mi][ni][2] + bias[n + 2]));
                    ov.w = f2b(gelu_f(acc[mi][ni][3] + bias[n + 3]));
                    *(ushort4*)(Cbf + (size_t)m * Nn + n) = ov;
                } else {  // EPI == 5
                    ushort4 ov;
                    ov.x = f2b(acc[mi][ni][0]); ov.y = f2b(acc[mi][ni][1]);
                    ov.z = f2b(acc[mi][ni][2]); ov.w = f2b(acc[mi][ni][3]);
                    *(ushort4*)(Cbf + (size_t)bz * sC + (size_t)m * Nn + n) = ov;
                }
            }
    }
}

// ---------------------------------------------------------------------------
// Reduce 8 split-K slices -> bf16 Gt [B, 256, 384]
// ---------------------------------------------------------------------------
__global__ __launch_bounds__(256) void gred(
    const float* __restrict__ part, u16* __restrict__ Gtb)
{
    int idx = blockIdx.x * 256 + threadIdx.x;      // over B*P*C
    int b = idx / (PDIM * CDIM);
    int e = idx % (PDIM * CDIM);
    float s = 0.f;
#pragma unroll
    for (int j = 0; j < 8; j++)
        s += part[((size_t)(b * 8 + j)) * (PDIM * CDIM) + e];
    Gtb[idx] = f2b(s);
}

// ---------------------------------------------------------------------------
// Column sum-of-squares of q_bf [B,N,C] over N (256-token chunks)
// ---------------------------------------------------------------------------
__global__ __launch_bounds__(128) void colsumsq(
    const u16* __restrict__ q, float* __restrict__ pcs)
{
    int c = blockIdx.x * 128 + threadIdx.x;
    int b = blockIdx.z;
    int chunk = blockIdx.y;
    const u16* qp = q + ((size_t)b * NTOK + chunk * 256) * CDIM + c;
    float s = 0.f;
#pragma unroll 4
    for (int i = 0; i < 256; i++) { float v = b2f(qp[(size_t)i * CDIM]); s += v * v; }
    pcs[(size_t)chunk * (BDIM * CDIM) + b * CDIM + c] = s;
}

__global__ __launch_bounds__(256) void colsumred(
    const float* __restrict__ pcs, float* __restrict__ css)
{
    int idx = blockIdx.x * 256 + threadIdx.x;
    if (idx < BDIM * CDIM) {
        float s = 0.f;
#pragma unroll
        for (int j = 0; j < 16; j++) s += pcs[(size_t)j * (BDIM * CDIM) + idx];
        css[idx] = s;
    }
}

// ---------------------------------------------------------------------------
// From kpvp_t [b, p, 0:384]=kp, [b, p, 384:768]=vp (f32):
// kps [bh, p, d] scaled bf16;  vpb [bh, d, p] bf16
// ---------------------------------------------------------------------------
__global__ __launch_bounds__(256) void scalepack2(
    const float* __restrict__ kpvp, const float* __restrict__ css,
    const float* __restrict__ temp, u16* __restrict__ kps, u16* __restrict__ vpb)
{
    int idx = blockIdx.x * 256 + threadIdx.x;      // over B*P*C
    int c = idx % CDIM;
    int t = idx / CDIM;
    int p = t & 255;
    int b = t >> 8;
    int h = c / HDIM, d = c % HDIM;
    const float* row = kpvp + ((size_t)b * PDIM + p) * (2 * CDIM);
    float kv = row[c];
    float vv = row[CDIM + c];
    float nrm = fmaxf(sqrtf(css[b * CDIM + c]), 1e-12f);
    float sc = temp[h] / nrm;
    int bh = b * NH + h;
    kps[((size_t)bh * PDIM + p) * HDIM + d] = f2b(kv * sc);
    vpb[((size_t)bh * HDIM + d) * PDIM + p] = f2b(vv);
}

// ---------------------------------------------------------------------------
// Fused attention: per (ntile of 64 tokens, h, b). Output bf16 (scrambled).
// ---------------------------------------------------------------------------
__global__ __launch_bounds__(256) void attn_fused(
    const u16* __restrict__ qbf, const u16* __restrict__ kps,
    const u16* __restrict__ vpb, u16* __restrict__ o_scr)
{
    __shared__ u16 vp_l[48 * 264];   // [d][p] pad 256->264
    __shared__ u16 un[64 * 264];     // union: kp_l [256][56] then p_l [64][264]
    u16* kp_l = un;
    u16* p_l = un;

    int nt = blockIdx.x, h = blockIdx.y, b = blockIdx.z;
    int tid = threadIdx.x, wave = tid >> 6, lane = tid & 63;
    int lm = lane & 15, lkb = lane >> 4;
    const u16* kpsb = kps + (size_t)(b * NH + h) * PDIM * HDIM;
    const u16* vpbb = vpb + (size_t)(b * NH + h) * HDIM * PDIM;

    for (int i = tid; i < 1536; i += 256) {      // 256 rows x 6 uint4
        int row = i / 6, ch = i % 6;
        *(uint4*)&kp_l[row * 56 + ch * 8] = *(const uint4*)(kpsb + row * 48 + ch * 8);
    }
    for (int i = tid; i < 1536; i += 256) {      // 48 rows x 32 uint4
        int row = i / 32, ch = i % 32;
        *(uint4*)&vp_l[row * 264 + ch * 8] = *(const uint4*)(vpbb + row * 256 + ch * 8);
    }
    __syncthreads();

    int t0 = nt * 64 + wave * 16;
    const u16* qb = qbf + ((size_t)b * NTOK + t0 + lm) * CDIM + h * HDIM;
    bf16x8 a0 = *(const bf16x8*)(qb + lkb * 8);
    bf16x8 a1 = bzero8();
    if (lkb < 2) a1 = *(const bf16x8*)(qb + 32 + lkb * 8);

    f32x4 s[16];
#pragma unroll
    for (int pi = 0; pi < 16; pi++) {
        f32x4 acc = f32x4{0.f, 0.f, 0.f, 0.f};
        bf16x8 b0 = *(const bf16x8*)&kp_l[(pi * 16 + lm) * 56 + lkb * 8];
        acc = __builtin_amdgcn_mfma_f32_16x16x32_bf16(a0, b0, acc, 0, 0, 0);
        bf16x8 b1 = bzero8();
        if (lkb < 2) b1 = *(const bf16x8*)&kp_l[(pi * 16 + lm) * 56 + 32 + lkb * 8];
        acc = __builtin_amdgcn_mfma_f32_16x16x32_bf16(a1, b1, acc, 0, 0, 0);
        s[pi] = acc;
    }
    __syncthreads();   // all QK^T reads of kp_l done before p_l overwrites it

    // softmax over 256 cols
#pragma unroll
    for (int r = 0; r < 4; r++) {
        float mx = s[0][r];
#pragma unroll
        for (int pi = 1; pi < 16; pi++) mx = fmaxf(mx, s[pi][r]);
        for (int m = 1; m < 16; m <<= 1) mx = fmaxf(mx, __shfl_xor(mx, m, 64));
        float e[16];
        float sum = 0.f;
#pragma unroll
        for (int pi = 0; pi < 16; pi++) { e[pi] = __expf(s[pi][r] - mx); sum += e[pi]; }
        for (int m = 1; m < 16; m <<= 1) sum += __shfl_xor(sum, m, 64);
        float inv = 1.0f / sum;
        int tl = wave * 16 + lkb * 4 + r;
#pragma unroll
        for (int pi = 0; pi < 16; pi++)
            p_l[tl * 264 + pi * 16 + lm] = f2b(e[pi] * inv);
    }
    __syncthreads();

    // o = p @ vp^T : per wave 16 tokens x 48 d, K=256
    f32x4 oa[3];
#pragma unroll
    for (int di = 0; di < 3; di++) oa[di] = f32x4{0.f, 0.f, 0.f, 0.f};
#pragma unroll
    for (int ksl = 0; ksl < 8; ksl++) {
        bf16x8 pa = *(const bf16x8*)&p_l[(wave * 16 + lm) * 264 + ksl * 32 + lkb * 8];
#pragma unroll
        for (int di = 0; di < 3; di++) {
            bf16x8 vb = *(const bf16x8*)&vp_l[(di * 16 + lm) * 264 + ksl * 32 + lkb * 8];
            oa[di] = __builtin_amdgcn_mfma_f32_16x16x32_bf16(pa, vb, oa[di], 0, 0, 0);
        }
    }
    size_t obase = (size_t)b * ((size_t)NTOK * CDIM);
#pragma unroll
    for (int di = 0; di < 3; di++) {
        int d = di * 16 + lm;
        int n0 = t0 + lkb * 4;
        ushort4 ov;
        ov.x = f2b(oa[di][0]); ov.y = f2b(oa[di][1]);
        ov.z = f2b(oa[di][2]); ov.w = f2b(oa[di][3]);
        *(ushort4*)(o_scr + obase + (size_t)(d * NH + h) * NTOK + n0) = ov;
    }
}

// ---------------------------------------------------------------------------
// LayerNorm over bf16 rows of 384, write bf16. block 128, one row per block.
// ---------------------------------------------------------------------------
__global__ __launch_bounds__(128) void ln_kernel(
    const u16* __restrict__ o, const float* __restrict__ gamma,
    const float* __restrict__ beta, u16* __restrict__ outbf)
{
    int row = blockIdx.x;
    const u16* rp = o + (size_t)row * CDIM;
    int tid = threadIdx.x;
    float v0 = b2f(rp[tid]), v1 = b2f(rp[tid + 128]), v2 = b2f(rp[tid + 256]);
    float s = v0 + v1 + v2;
    for (int m = 1; m < 64; m <<= 1) s += __shfl_xor(s, m, 64);
    __shared__ float red[2];
    if ((tid & 63) == 0) red[tid >> 6] = s;
    __syncthreads();
    float mean = (red[0] + red[1]) * (1.0f / CDIM);
    float d0 = v0 - mean, d1 = v1 - mean, d2 = v2 - mean;
    float qv = d0 * d0 + d1 * d1 + d2 * d2;
    for (int m = 1; m < 64; m <<= 1) qv += __shfl_xor(qv, m, 64);
    __shared__ float red2[2];
    if ((tid & 63) == 0) red2[tid >> 6] = qv;
    __syncthreads();
    float var = (red2[0] + red2[1]) * (1.0f / CDIM);
    float rstd = rsqrtf(var + 1e-5f);
    u16* op = outbf + (size_t)row * CDIM;
    op[tid]       = f2b(d0 * rstd * gamma[tid]       + beta[tid]);
    op[tid + 128] = f2b(d1 * rstd * gamma[tid + 128] + beta[tid + 128]);
    op[tid + 256] = f2b(d2 * rstd * gamma[tid + 256] + beta[tid + 256]);
}

// ---------------------------------------------------------------------------
extern "C" void kernel_launch(void* const* d_in, const int* in_sizes, int n_in,
                              void* d_out, int out_size, void* d_ws, size_t ws_size,
                              hipStream_t stream)
{
    (void)in_sizes; (void)n_in; (void)out_size; (void)ws_size;
    const float* x    = (const float*)d_in[0];
    const float* y    = (const float*)d_in[1];
    const float* Wq   = (const float*)d_in[2];
    const float* Wkv  = (const float*)d_in[3];
    const float* EF   = (const float*)d_in[4];
    const float* temp = (const float*)d_in[5];
    const float* gam  = (const float*)d_in[6];
    const float* bet  = (const float*)d_in[7];
    const float* w1   = (const float*)d_in[8];
    const float* b1   = (const float*)d_in[9];
    const float* w2   = (const float*)d_in[10];
    const float* b2   = (const float*)d_in[11];
    float* out = (float*)d_out;

    char* w = (char*)d_ws;
    size_t off = 0;
    auto alloc = [&](size_t nb) { size_t o = off; off += (nb + 255) & ~(size_t)255; return o; };
    u16*   xt_bf = (u16*)(w + alloc((size_t)BDIM * NTOK * CDIM * 2));
    u16*   x_bf  = (u16*)(w + alloc((size_t)BDIM * NTOK * CDIM * 2)); // reused as ln_bf
    u16*   q_bf  = (u16*)(w + alloc((size_t)BDIM * NTOK * CDIM * 2));
    u16*   Wqt   = (u16*)(w + alloc((size_t)CDIM * CDIM * 2));
    u16*   EFt   = (u16*)(w + alloc((size_t)PDIM * NTOK * 2));
    u16*   w1t   = (u16*)(w + alloc((size_t)1536 * CDIM * 2));
    u16*   w2t   = (u16*)(w + alloc((size_t)CDIM * 1536 * 2));
    u16*   Wkvt  = (u16*)(w + alloc((size_t)768 * CDIM * 2));
    float* gpart = (float*)(w + alloc((size_t)BDIM * NTOK * 1536 * 2)); // union w/ h1bf
    u16*   h1bf  = (u16*)gpart;
    u16*   Gt_bf = (u16*)(w + alloc((size_t)BDIM * PDIM * CDIM * 2));
    float* kpvpf = (float*)(w + alloc((size_t)BDIM * PDIM * 2 * CDIM * 4));
    float* pcs   = (float*)(w + alloc((size_t)16 * BDIM * CDIM * 4));
    float* css   = (float*)(w + alloc((size_t)BDIM * CDIM * 4));
    u16*   kps   = (u16*)(w + alloc((size_t)BDIM * NH * PDIM * HDIM * 2));
    u16*   vpb   = (u16*)(w + alloc((size_t)BDIM * NH * HDIM * PDIM * 2));
    u16*   o_scr = (u16*)(w + alloc((size_t)BDIM * NTOK * CDIM * 2));   // bf16
    u16*   ln_bf = x_bf;

    // ---- ONE launch for all 6 transposes -------------------------------
    TDescs td;
    auto setd = [&](int i, const float* s, u16* dT, u16* dC, int R, int C,
                    int nz, int start) {
        td.d[i].src = s; td.d[i].dT = dT; td.d[i].dC = dC;
        td.d[i].R = R; td.d[i].C = C;
        td.d[i].ntx = C / 32; td.d[i].nty = R / 32;
        td.d[i].start = start;
        return start + (C / 32) * (R / 32) * nz;
    };
    int tot = 0;
    tot = setd(0, x,   xt_bf, x_bf,  CDIM, NTOK, BDIM, tot);   // 6144
    tot = setd(1, Wq,  Wqt,  nullptr, CDIM, CDIM, 1, tot);     // 144
    tot = setd(2, EF,  EFt,  nullptr, NTOK, PDIM, 1, tot);     // 1024
    tot = setd(3, w1,  w1t,  nullptr, CDIM, 1536, 1, tot);     // 576
    tot = setd(4, w2,  w2t,  nullptr, 1536, CDIM, 1, tot);     // 576
    tot = setd(5, Wkv, Wkvt, nullptr, CDIM, 768,  1, tot);     // 288 -> 8752
    multi_transpose<<<dim3(tot, 8, 1), dim3(32, 8, 1), 0, stream>>>(td);

    // Gt partials: Gt[b][p][c] = sum_n EFt[p,n] * x_bf[b][c][n], split-K 8
    gemm_bt<4, 64, 128, 0><<<dim3(PDIM / 64, CDIM / 128, BDIM * 8), 256, 0, stream>>>(
        EFt, x_bf, PDIM, CDIM, NTOK, 0, (long)CDIM * NTOK, (long)PDIM * CDIM, 0,
        gpart, nullptr, nullptr, nullptr, nullptr);
    gred<<<dim3((BDIM * PDIM * CDIM) / 256, 1, 1), 256, 0, stream>>>(gpart, Gt_bf);

    // q = xt @ Wq -> bf16 q_bf (XCD-chunked 1-D grid, nBN=3)
    gemm_bt<5, 64, 128, 1><<<dim3((NTOK / 64) * (CDIM / 128), 1, BDIM), 256, 0, stream>>>(
        xt_bf, Wqt, NTOK, CDIM, CDIM, (long)NTOK * CDIM, 0, (long)NTOK * CDIM, CDIM / 128,
        nullptr, nullptr, q_bf, nullptr, nullptr);

    colsumsq<<<dim3(CDIM / 128, 16, BDIM), 128, 0, stream>>>(q_bf, pcs);
    colsumred<<<dim3(6, 1, 1), 256, 0, stream>>>(pcs, css);

    // kpvp_t[b] = Gt_bf[b] @ Wkvt^T : [256, 768] f32
    gemm_bt<0, 64, 128, 0><<<dim3(PDIM / 64, 768 / 128, BDIM), 256, 0, stream>>>(
        Gt_bf, Wkvt, PDIM, 768, CDIM, (long)PDIM * CDIM, 0, (long)PDIM * 768, 0,
        kpvpf, nullptr, nullptr, nullptr, nullptr);

    scalepack2<<<dim3((BDIM * PDIM * CDIM) / 256, 1, 1), 256, 0, stream>>>(
        kpvpf, css, temp, kps, vpb);

    attn_fused<<<dim3(NTOK / 64, NH, BDIM), 256, 0, stream>>>(q_bf, kps, vpb, o_scr);

    ln_kernel<<<dim3(BDIM * NTOK, 1, 1), 128, 0, stream>>>(o_scr, gam, bet, ln_bf);

    // MLP1: gelu(ln @ w1 + b1) -> bf16 [16384,1536]
    gemm_bt<1, 64, 128, 1><<<dim3(((BDIM * NTOK) / 64) * (1536 / 128), 1, 1), 256, 0, stream>>>(
        ln_bf, w1t, BDIM * NTOK, 1536, CDIM, 0, 0, 0, 1536 / 128,
        nullptr, b1, h1bf, nullptr, nullptr);
    // MLP2: h1 @ w2 + b2 + y (transposed add) -> f32 out [B,C,N]
    gemm_bt<2, 64, 128, 1><<<dim3(((BDIM * NTOK) / 64) * (CDIM / 128), 1, 1), 256, 0, stream>>>(
        h1bf, w2t, BDIM * NTOK, CDIM, 1536, 0, 0, 0, CDIM / 128,
        nullptr, b2, nullptr, y, out);
}

// Round 14
// 221.295 us; speedup vs baseline: 1.3057x; 1.3057x over previous
//
#include <hip/hip_runtime.h>

#define NH 8
#define CDIM 384
#define HDIM 48
#define NTOK 4096
#define PDIM 256
#define BDIM 4

typedef unsigned short u16;
typedef unsigned int u32;
typedef __bf16 bf16x8 __attribute__((ext_vector_type(8)));
typedef float f32x4 __attribute__((ext_vector_type(4)));

__device__ __forceinline__ u16 f2b(float f) {
    u32 u = __float_as_uint(f);
    u = (u + 0x7fffu + ((u >> 16) & 1u)) >> 16;   // RNE bf16
    return (u16)u;
}
__device__ __forceinline__ float b2f(u16 u) {
    return __uint_as_float(((u32)u) << 16);
}

__device__ __forceinline__ bf16x8 bzero8() {
    bf16x8 v;
#pragma unroll
    for (int i = 0; i < 8; i++) v[i] = (__bf16)0.0f;
    return v;
}

__device__ __forceinline__ void gload16(const u16* g, u16* l) {
    __builtin_amdgcn_global_load_lds(
        (const __attribute__((address_space(1))) void*)g,
        (__attribute__((address_space(3))) void*)l, 16, 0, 0);
}

// tanh-form GELU, max abs err ~3e-4 vs exact erf form
__device__ __forceinline__ float gelu_f(float x) {
    float z = 0.7978845608028654f * (x + 0.044715f * x * x * x);
    float e = __expf(2.0f * z);
    float t = 1.0f - 2.0f / (e + 1.0f);
    return 0.5f * x * (1.0f + t);
}

// ---------------------------------------------------------------------------
// Unified multi-transpose: ALL f32->bf16 transposes in ONE launch.
// desc i: src f32 [nz, R, C] -> dT bf16 [nz, C, R]; optional dC bf16 [nz,R,C].
// 32x32 tiles, block (32,8). Flat 1-D grid over all descs' tiles.
// ---------------------------------------------------------------------------
#define NDESC 6
struct TDesc {
    const float* src; u16* dT; u16* dC;
    int R, C, ntx, nty, start;   // start = first flat tile id of this desc
};
struct TDescs { TDesc d[NDESC]; };

__global__ __launch_bounds__(256) void multi_transpose(TDescs td)
{
    __shared__ float tile[32][33];
    int t = blockIdx.x;
    int di = 0;
#pragma unroll
    for (int i = 1; i < NDESC; i++) if (t >= td.d[i].start) di = i;
    const TDesc& D = td.d[di];
    int lt = t - D.start;
    int perZ = D.ntx * D.nty;
    int z = lt / perZ;
    int rr = lt % perZ;
    int r0 = (rr / D.ntx) * 32, c0 = (rr % D.ntx) * 32;
    size_t zoff = (size_t)z * D.R * D.C;
    const float* inp = D.src + zoff;
    int tx = threadIdx.x, ty = threadIdx.y;
#pragma unroll
    for (int i = 0; i < 4; i++) {
        int r = r0 + ty + i * 8;
        float v = inp[(size_t)r * D.C + c0 + tx];
        tile[ty + i * 8][tx] = v;
        if (D.dC) D.dC[zoff + (size_t)r * D.C + c0 + tx] = f2b(v);
    }
    __syncthreads();
    u16* oT = D.dT + zoff;
#pragma unroll
    for (int i = 0; i < 4; i++) {
        int c = c0 + ty + i * 8;
        oT[(size_t)c * D.R + r0 + tx] = f2b(tile[tx][ty + i * 8]);
    }
}

// ---------------------------------------------------------------------------
// GEMM: C[M,N] = A[M,K](bf16,row) @ Bt[N,K](bf16,row)^T, f32 accum.
// Tile BMv x BNv, BK=32, 4 waves (2x2), 16x16x32 MFMA.
// 3-deep LDS ring + counted vmcnt; ONE s_barrier per K-step.
// T2 swizzle both-sides (source-chunk permute ch^=(r>>1)&3, same on read).
// SWZ=1: 1-D grid, XCD-chunked remap (T1).
// SWAPC (EPI != 2): swapped operands -> packed float4/ushort4 stores.
// EPI 0: f32 store; EPI 1: gelu->bf16; EPI 2: +bias+Y transposed f32 out;
// EPI 4: split-8 K partials; EPI 5: bf16 store with batch offset.
// ---------------------------------------------------------------------------
template <int EPI, int BMv, int BNv, int SWZ>
__global__ __launch_bounds__(256) void gemm_bt(
    const u16* __restrict__ A, const u16* __restrict__ Bt,
    int M, int Nn, int K, long sA, long sB, long sC, int nBN,
    float* __restrict__ Cf, const float* __restrict__ bias,
    u16* __restrict__ Cbf, const float* __restrict__ Yin, float* __restrict__ Out)
{
    constexpr bool SWAPC = (EPI != 2);
    const int MT = BMv / 32, NT = BNv / 32;
    const int BK = 32, LP = 32;
    __shared__ u16 lsA[3][BMv * LP];
    __shared__ u16 lsB[3][BNv * LP];
    const int tid = threadIdx.x;
    const int wave = tid >> 6, lane = tid & 63;
    const int lm = lane & 15, lkb = lane >> 4;
    int bm, bn;
    const int bz = blockIdx.z;
    if (SWZ) {
        int nwg = gridDim.x;                     // divisible by 8
        int w = ((blockIdx.x & 7) * (nwg >> 3)) + (blockIdx.x >> 3);
        bm = w / nBN; bn = w % nBN;
    } else {
        bm = blockIdx.x; bn = blockIdx.y;
    }
    int bb = bz, ks = 0, ke = K;
    if (EPI == 4) { bb = bz >> 3; ks = (bz & 7) * (K >> 3); ke = ks + (K >> 3); }
    const u16* Ab = A + (size_t)bb * sA;
    const u16* Bb = Bt + (size_t)bb * sB;
    const int wm = (wave >> 1) * (BMv / 2), wn = (wave & 1) * (BNv / 2);

    f32x4 acc[MT][NT];
#pragma unroll
    for (int i = 0; i < MT; i++)
#pragma unroll
        for (int j = 0; j < NT; j++) acc[i][j] = f32x4{0.f, 0.f, 0.f, 0.f};

    // swizzled global source chunk: LDS chunk (r, c) holds global chunk c^((r>>1)&3)
    auto stage = [&](int k0, int c) {
#pragma unroll
        for (int j = 0; j < BMv / 64; j++) {
            int cb = (j * 4 + wave) * 64;
            int q = cb + lane;
            int r = q >> 2, ch = (q & 3) ^ ((r >> 1) & 3);
            gload16(Ab + (size_t)(bm * BMv + r) * K + k0 + ch * 8, &lsA[c][cb * 8]);
        }
#pragma unroll
        for (int j = 0; j < BNv / 64; j++) {
            int cb = (j * 4 + wave) * 64;
            int q = cb + lane;
            int r = q >> 2, ch = (q & 3) ^ ((r >> 1) & 3);
            gload16(Bb + (size_t)(bn * BNv + r) * K + k0 + ch * 8, &lsB[c][cb * 8]);
        }
    };
    // loads per stage per thread
    constexpr int NLD = (BMv + BNv) / 64;
    #define WAIT_LD() do { \
        if constexpr (NLD == 3)      asm volatile("s_waitcnt vmcnt(3)" ::: "memory"); \
        else if constexpr (NLD == 4) asm volatile("s_waitcnt vmcnt(4)" ::: "memory"); \
        else                         asm volatile("s_waitcnt vmcnt(6)" ::: "memory"); \
    } while (0)

    const int nt = (ke - ks) / BK;   // all launches have nt >= 8
    stage(ks, 0);
    stage(ks + BK, 1);
    WAIT_LD();                        // tile 0 complete (tile 1 in flight)
    __builtin_amdgcn_s_barrier();

    for (int t = 0; t < nt; ++t) {
        const int cur = t % 3;
        if (t + 2 < nt) stage(ks + (t + 2) * BK, (t + 2) % 3);
        bf16x8 af[MT], bfr[NT];
#pragma unroll
        for (int m = 0; m < MT; m++) {
            int R = wm + m * 16 + lm;
            af[m] = *(const bf16x8*)&lsA[cur][R * LP + ((lkb ^ ((R >> 1) & 3)) * 8)];
        }
#pragma unroll
        for (int n = 0; n < NT; n++) {
            int R = wn + n * 16 + lm;
            bfr[n] = *(const bf16x8*)&lsB[cur][R * LP + ((lkb ^ ((R >> 1) & 3)) * 8)];
        }
#pragma unroll
        for (int mi = 0; mi < MT; mi++)
#pragma unroll
            for (int ni = 0; ni < NT; ni++) {
                if (SWAPC)
                    acc[mi][ni] = __builtin_amdgcn_mfma_f32_16x16x32_bf16(
                        bfr[ni], af[mi], acc[mi][ni], 0, 0, 0);
                else
                    acc[mi][ni] = __builtin_amdgcn_mfma_f32_16x16x32_bf16(
                        af[mi], bfr[ni], acc[mi][ni], 0, 0, 0);
            }
        if (t + 1 < nt) {
            if (t + 2 < nt) { WAIT_LD(); }
            else { asm volatile("s_waitcnt vmcnt(0)" ::: "memory"); }
            __builtin_amdgcn_s_barrier();
        }
    }
    #undef WAIT_LD

    if (EPI == 2) {
        // unswapped: acc[.][.][r] spans 4 consecutive m (= tok)
#pragma unroll
        for (int mi = 0; mi < MT; mi++)
#pragma unroll
            for (int ni = 0; ni < NT; ni++) {
                int m0 = bm * BMv + wm + mi * 16 + lkb * 4;
                int n = bn * BNv + wn + ni * 16 + lm;
                int b = m0 >> 12, tok = m0 & 4095;
                size_t oi = ((size_t)b * CDIM + n) * NTOK + tok;
                float4 yv = *(const float4*)(Yin + oi);
                float bv = bias[n];
                float4 ov;
                ov.x = acc[mi][ni][0] + bv + yv.x;
                ov.y = acc[mi][ni][1] + bv + yv.y;
                ov.z = acc[mi][ni][2] + bv + yv.z;
                ov.w = acc[mi][ni][3] + bv + yv.w;
                *(float4*)(Out + oi) = ov;
            }
    } else {
        // SWAPC: acc[.][.][r] spans 4 consecutive n
#pragma unroll
        for (int mi = 0; mi < MT; mi++)
#pragma unroll
            for (int ni = 0; ni < NT; ni++) {
                int m = bm * BMv + wm + mi * 16 + lm;
                int n = bn * BNv + wn + ni * 16 + lkb * 4;
                if (EPI == 0 || EPI == 4) {
                    *(float4*)(Cf + (size_t)bz * sC + (size_t)m * Nn + n) =
                        float4{acc[mi][ni][0], acc[mi][ni][1],
                               acc[mi][ni][2], acc[mi][ni][3]};
                } else if (EPI == 1) {
                    ushort4 ov;
                    ov.x = f2b(gelu_f(acc[mi][ni][0] + bias[n + 0]));
                    ov.y = f2b(gelu_f(acc[mi][ni][1] + bias[n + 1]));
                    ov.z = f2b(gelu_f(acc[mi][ni][2] + bias[n + 2]));
                    ov.w = f2b(gelu_f(acc[mi][ni][3] + bias[n + 3]));
                    *(ushort4*)(Cbf + (size_t)m * Nn + n) = ov;
                } else {  // EPI == 5
                    ushort4 ov;
                    ov.x = f2b(acc[mi][ni][0]); ov.y = f2b(acc[mi][ni][1]);
                    ov.z = f2b(acc[mi][ni][2]); ov.w = f2b(acc[mi][ni][3]);
                    *(ushort4*)(Cbf + (size_t)bz * sC + (size_t)m * Nn + n) = ov;
                }
            }
    }
}

// ---------------------------------------------------------------------------
// Reduce 8 split-K slices -> bf16 Gt [B, 256, 384]
// ---------------------------------------------------------------------------
__global__ __launch_bounds__(256) void gred(
    const float* __restrict__ part, u16* __restrict__ Gtb)
{
    int idx = blockIdx.x * 256 + threadIdx.x;      // over B*P*C
    int b = idx / (PDIM * CDIM);
    int e = idx % (PDIM * CDIM);
    float s = 0.f;
#pragma unroll
    for (int j = 0; j < 8; j++)
        s += part[((size_t)(b * 8 + j)) * (PDIM * CDIM) + e];
    Gtb[idx] = f2b(s);
}

// ---------------------------------------------------------------------------
// Column sum-of-squares of q_bf [B,N,C] over N (256-token chunks)
// ---------------------------------------------------------------------------
__global__ __launch_bounds__(128) void colsumsq(
    const u16* __restrict__ q, float* __restrict__ pcs)
{
    int c = blockIdx.x * 128 + threadIdx.x;
    int b = blockIdx.z;
    int chunk = blockIdx.y;
    const u16* qp = q + ((size_t)b * NTOK + chunk * 256) * CDIM + c;
    float s = 0.f;
#pragma unroll 4
    for (int i = 0; i < 256; i++) { float v = b2f(qp[(size_t)i * CDIM]); s += v * v; }
    pcs[(size_t)chunk * (BDIM * CDIM) + b * CDIM + c] = s;
}

__global__ __launch_bounds__(256) void colsumred(
    const float* __restrict__ pcs, float* __restrict__ css)
{
    int idx = blockIdx.x * 256 + threadIdx.x;
    if (idx < BDIM * CDIM) {
        float s = 0.f;
#pragma unroll
        for (int j = 0; j < 16; j++) s += pcs[(size_t)j * (BDIM * CDIM) + idx];
        css[idx] = s;
    }
}

// ---------------------------------------------------------------------------
// From kpvp_t [b, p, 0:384]=kp, [b, p, 384:768]=vp (f32):
// kps [bh, p, d] scaled bf16;  vpb [bh, d, p] bf16
// ---------------------------------------------------------------------------
__global__ __launch_bounds__(256) void scalepack2(
    const float* __restrict__ kpvp, const float* __restrict__ css,
    const float* __restrict__ temp, u16* __restrict__ kps, u16* __restrict__ vpb)
{
    int idx = blockIdx.x * 256 + threadIdx.x;      // over B*P*C
    int c = idx % CDIM;
    int t = idx / CDIM;
    int p = t & 255;
    int b = t >> 8;
    int h = c / HDIM, d = c % HDIM;
    const float* row = kpvp + ((size_t)b * PDIM + p) * (2 * CDIM);
    float kv = row[c];
    float vv = row[CDIM + c];
    float nrm = fmaxf(sqrtf(css[b * CDIM + c]), 1e-12f);
    float sc = temp[h] / nrm;
    int bh = b * NH + h;
    kps[((size_t)bh * PDIM + p) * HDIM + d] = f2b(kv * sc);
    vpb[((size_t)bh * HDIM + d) * PDIM + p] = f2b(vv);
}

// ---------------------------------------------------------------------------
// Fused attention: per (ntile of 64 tokens, h, b). Output bf16 (scrambled).
// ---------------------------------------------------------------------------
__global__ __launch_bounds__(256) void attn_fused(
    const u16* __restrict__ qbf, const u16* __restrict__ kps,
    const u16* __restrict__ vpb, u16* __restrict__ o_scr)
{
    __shared__ u16 vp_l[48 * 264];   // [d][p] pad 256->264
    __shared__ u16 un[64 * 264];     // union: kp_l [256][56] then p_l [64][264]
    u16* kp_l = un;
    u16* p_l = un;

    int nt = blockIdx.x, h = blockIdx.y, b = blockIdx.z;
    int tid = threadIdx.x, wave = tid >> 6, lane = tid & 63;
    int lm = lane & 15, lkb = lane >> 4;
    const u16* kpsb = kps + (size_t)(b * NH + h) * PDIM * HDIM;
    const u16* vpbb = vpb + (size_t)(b * NH + h) * HDIM * PDIM;

    for (int i = tid; i < 1536; i += 256) {      // 256 rows x 6 uint4
        int row = i / 6, ch = i % 6;
        *(uint4*)&kp_l[row * 56 + ch * 8] = *(const uint4*)(kpsb + row * 48 + ch * 8);
    }
    for (int i = tid; i < 1536; i += 256) {      // 48 rows x 32 uint4
        int row = i / 32, ch = i % 32;
        *(uint4*)&vp_l[row * 264 + ch * 8] = *(const uint4*)(vpbb + row * 256 + ch * 8);
    }
    __syncthreads();

    int t0 = nt * 64 + wave * 16;
    const u16* qb = qbf + ((size_t)b * NTOK + t0 + lm) * CDIM + h * HDIM;
    bf16x8 a0 = *(const bf16x8*)(qb + lkb * 8);
    bf16x8 a1 = bzero8();
    if (lkb < 2) a1 = *(const bf16x8*)(qb + 32 + lkb * 8);

    f32x4 s[16];
#pragma unroll
    for (int pi = 0; pi < 16; pi++) {
        f32x4 acc = f32x4{0.f, 0.f, 0.f, 0.f};
        bf16x8 b0 = *(const bf16x8*)&kp_l[(pi * 16 + lm) * 56 + lkb * 8];
        acc = __builtin_amdgcn_mfma_f32_16x16x32_bf16(a0, b0, acc, 0, 0, 0);
        bf16x8 b1 = bzero8();
        if (lkb < 2) b1 = *(const bf16x8*)&kp_l[(pi * 16 + lm) * 56 + 32 + lkb * 8];
        acc = __builtin_amdgcn_mfma_f32_16x16x32_bf16(a1, b1, acc, 0, 0, 0);
        s[pi] = acc;
    }
    __syncthreads();   // all QK^T reads of kp_l done before p_l overwrites it

    // softmax over 256 cols
#pragma unroll
    for (int r = 0; r < 4; r++) {
        float mx = s[0][r];
#pragma unroll
        for (int pi = 1; pi < 16; pi++) mx = fmaxf(mx, s[pi][r]);
        for (int m = 1; m < 16; m <<= 1) mx = fmaxf(mx, __shfl_xor(mx, m, 64));
        float e[16];
        float sum = 0.f;
#pragma unroll
        for (int pi = 0; pi < 16; pi++) { e[pi] = __expf(s[pi][r] - mx); sum += e[pi]; }
        for (int m = 1; m < 16; m <<= 1) sum += __shfl_xor(sum, m, 64);
        float inv = 1.0f / sum;
        int tl = wave * 16 + lkb * 4 + r;
#pragma unroll
        for (int pi = 0; pi < 16; pi++)
            p_l[tl * 264 + pi * 16 + lm] = f2b(e[pi] * inv);
    }
    __syncthreads();

    // o = p @ vp^T : per wave 16 tokens x 48 d, K=256
    f32x4 oa[3];
#pragma unroll
    for (int di = 0; di < 3; di++) oa[di] = f32x4{0.f, 0.f, 0.f, 0.f};
#pragma unroll
    for (int ksl = 0; ksl < 8; ksl++) {
        bf16x8 pa = *(const bf16x8*)&p_l[(wave * 16 + lm) * 264 + ksl * 32 + lkb * 8];
#pragma unroll
        for (int di = 0; di < 3; di++) {
            bf16x8 vb = *(const bf16x8*)&vp_l[(di * 16 + lm) * 264 + ksl * 32 + lkb * 8];
            oa[di] = __builtin_amdgcn_mfma_f32_16x16x32_bf16(pa, vb, oa[di], 0, 0, 0);
        }
    }
    size_t obase = (size_t)b * ((size_t)NTOK * CDIM);
#pragma unroll
    for (int di = 0; di < 3; di++) {
        int d = di * 16 + lm;
        int n0 = t0 + lkb * 4;
        ushort4 ov;
        ov.x = f2b(oa[di][0]); ov.y = f2b(oa[di][1]);
        ov.z = f2b(oa[di][2]); ov.w = f2b(oa[di][3]);
        *(ushort4*)(o_scr + obase + (size_t)(d * NH + h) * NTOK + n0) = ov;
    }
}

// ---------------------------------------------------------------------------
// LayerNorm over bf16 rows of 384, write bf16. block 128, one row per block.
// ---------------------------------------------------------------------------
__global__ __launch_bounds__(128) void ln_kernel(
    const u16* __restrict__ o, const float* __restrict__ gamma,
    const float* __restrict__ beta, u16* __restrict__ outbf)
{
    int row = blockIdx.x;
    const u16* rp = o + (size_t)row * CDIM;
    int tid = threadIdx.x;
    float v0 = b2f(rp[tid]), v1 = b2f(rp[tid + 128]), v2 = b2f(rp[tid + 256]);
    float s = v0 + v1 + v2;
    for (int m = 1; m < 64; m <<= 1) s += __shfl_xor(s, m, 64);
    __shared__ float red[2];
    if ((tid & 63) == 0) red[tid >> 6] = s;
    __syncthreads();
    float mean = (red[0] + red[1]) * (1.0f / CDIM);
    float d0 = v0 - mean, d1 = v1 - mean, d2 = v2 - mean;
    float qv = d0 * d0 + d1 * d1 + d2 * d2;
    for (int m = 1; m < 64; m <<= 1) qv += __shfl_xor(qv, m, 64);
    __shared__ float red2[2];
    if ((tid & 63) == 0) red2[tid >> 6] = qv;
    __syncthreads();
    float var = (red2[0] + red2[1]) * (1.0f / CDIM);
    float rstd = rsqrtf(var + 1e-5f);
    u16* op = outbf + (size_t)row * CDIM;
    op[tid]       = f2b(d0 * rstd * gamma[tid]       + beta[tid]);
    op[tid + 128] = f2b(d1 * rstd * gamma[tid + 128] + beta[tid + 128]);
    op[tid + 256] = f2b(d2 * rstd * gamma[tid + 256] + beta[tid + 256]);
}

// ---------------------------------------------------------------------------
extern "C" void kernel_launch(void* const* d_in, const int* in_sizes, int n_in,
                              void* d_out, int out_size, void* d_ws, size_t ws_size,
                              hipStream_t stream)
{
    (void)in_sizes; (void)n_in; (void)out_size; (void)ws_size;
    const float* x    = (const float*)d_in[0];
    const float* y    = (const float*)d_in[1];
    const float* Wq   = (const float*)d_in[2];
    const float* Wkv  = (const float*)d_in[3];
    const float* EF   = (const float*)d_in[4];
    const float* temp = (const float*)d_in[5];
    const float* gam  = (const float*)d_in[6];
    const float* bet  = (const float*)d_in[7];
    const float* w1   = (const float*)d_in[8];
    const float* b1   = (const float*)d_in[9];
    const float* w2   = (const float*)d_in[10];
    const float* b2   = (const float*)d_in[11];
    float* out = (float*)d_out;

    char* w = (char*)d_ws;
    size_t off = 0;
    auto alloc = [&](size_t nb) { size_t o = off; off += (nb + 255) & ~(size_t)255; return o; };
    u16*   xt_bf = (u16*)(w + alloc((size_t)BDIM * NTOK * CDIM * 2));
    u16*   x_bf  = (u16*)(w + alloc((size_t)BDIM * NTOK * CDIM * 2)); // reused as ln_bf
    u16*   q_bf  = (u16*)(w + alloc((size_t)BDIM * NTOK * CDIM * 2));
    u16*   Wqt   = (u16*)(w + alloc((size_t)CDIM * CDIM * 2));
    u16*   EFt   = (u16*)(w + alloc((size_t)PDIM * NTOK * 2));
    u16*   w1t   = (u16*)(w + alloc((size_t)1536 * CDIM * 2));
    u16*   w2t   = (u16*)(w + alloc((size_t)CDIM * 1536 * 2));
    u16*   Wkvt  = (u16*)(w + alloc((size_t)768 * CDIM * 2));
    float* gpart = (float*)(w + alloc((size_t)BDIM * NTOK * 1536 * 2)); // union w/ h1bf
    u16*   h1bf  = (u16*)gpart;
    u16*   Gt_bf = (u16*)(w + alloc((size_t)BDIM * PDIM * CDIM * 2));
    float* kpvpf = (float*)(w + alloc((size_t)BDIM * PDIM * 2 * CDIM * 4));
    float* pcs   = (float*)(w + alloc((size_t)16 * BDIM * CDIM * 4));
    float* css   = (float*)(w + alloc((size_t)BDIM * CDIM * 4));
    u16*   kps   = (u16*)(w + alloc((size_t)BDIM * NH * PDIM * HDIM * 2));
    u16*   vpb   = (u16*)(w + alloc((size_t)BDIM * NH * HDIM * PDIM * 2));
    u16*   o_scr = (u16*)(w + alloc((size_t)BDIM * NTOK * CDIM * 2));   // bf16
    u16*   ln_bf = x_bf;

    // ---- ONE launch for all 6 transposes (grid = tot, NOT tot x 8!) ----
    TDescs td;
    auto setd = [&](int i, const float* s, u16* dT, u16* dC, int R, int C,
                    int nz, int start) {
        td.d[i].src = s; td.d[i].dT = dT; td.d[i].dC = dC;
        td.d[i].R = R; td.d[i].C = C;
        td.d[i].ntx = C / 32; td.d[i].nty = R / 32;
        td.d[i].start = start;
        return start + (C / 32) * (R / 32) * nz;
    };
    int tot = 0;
    tot = setd(0, x,   xt_bf, x_bf,  CDIM, NTOK, BDIM, tot);   // 6144
    tot = setd(1, Wq,  Wqt,  nullptr, CDIM, CDIM, 1, tot);     // 144
    tot = setd(2, EF,  EFt,  nullptr, NTOK, PDIM, 1, tot);     // 1024
    tot = setd(3, w1,  w1t,  nullptr, CDIM, 1536, 1, tot);     // 576
    tot = setd(4, w2,  w2t,  nullptr, 1536, CDIM, 1, tot);     // 576
    tot = setd(5, Wkv, Wkvt, nullptr, CDIM, 768,  1, tot);     // 288 -> 8752
    multi_transpose<<<dim3(tot, 1, 1), dim3(32, 8, 1), 0, stream>>>(td);

    // Gt partials: Gt[b][p][c] = sum_n EFt[p,n] * x_bf[b][c][n], split-K 8
    gemm_bt<4, 64, 128, 0><<<dim3(PDIM / 64, CDIM / 128, BDIM * 8), 256, 0, stream>>>(
        EFt, x_bf, PDIM, CDIM, NTOK, 0, (long)CDIM * NTOK, (long)PDIM * CDIM, 0,
        gpart, nullptr, nullptr, nullptr, nullptr);
    gred<<<dim3((BDIM * PDIM * CDIM) / 256, 1, 1), 256, 0, stream>>>(gpart, Gt_bf);

    // q = xt @ Wq -> bf16 q_bf (XCD-chunked 1-D grid, nBN=3)
    gemm_bt<5, 64, 128, 1><<<dim3((NTOK / 64) * (CDIM / 128), 1, BDIM), 256, 0, stream>>>(
        xt_bf, Wqt, NTOK, CDIM, CDIM, (long)NTOK * CDIM, 0, (long)NTOK * CDIM, CDIM / 128,
        nullptr, nullptr, q_bf, nullptr, nullptr);

    colsumsq<<<dim3(CDIM / 128, 16, BDIM), 128, 0, stream>>>(q_bf, pcs);
    colsumred<<<dim3(6, 1, 1), 256, 0, stream>>>(pcs, css);

    // kpvp_t[b] = Gt_bf[b] @ Wkvt^T : [256, 768] f32
    gemm_bt<0, 64, 128, 0><<<dim3(PDIM / 64, 768 / 128, BDIM), 256, 0, stream>>>(
        Gt_bf, Wkvt, PDIM, 768, CDIM, (long)PDIM * CDIM, 0, (long)PDIM * 768, 0,
        kpvpf, nullptr, nullptr, nullptr, nullptr);

    scalepack2<<<dim3((BDIM * PDIM * CDIM) / 256, 1, 1), 256, 0, stream>>>(
        kpvpf, css, temp, kps, vpb);

    attn_fused<<<dim3(NTOK / 64, NH, BDIM), 256, 0, stream>>>(q_bf, kps, vpb, o_scr);

    ln_kernel<<<dim3(BDIM * NTOK, 1, 1), 128, 0, stream>>>(o_scr, gam, bet, ln_bf);

    // MLP1: gelu(ln @ w1 + b1) -> bf16 [16384,1536]
    gemm_bt<1, 64, 128, 1><<<dim3(((BDIM * NTOK) / 64) * (1536 / 128), 1, 1), 256, 0, stream>>>(
        ln_bf, w1t, BDIM * NTOK, 1536, CDIM, 0, 0, 0, 1536 / 128,
        nullptr, b1, h1bf, nullptr, nullptr);
    // MLP2: h1 @ w2 + b2 + y (transposed add) -> f32 out [B,C,N]
    gemm_bt<2, 64, 128, 1><<<dim3(((BDIM * NTOK) / 64) * (CDIM / 128), 1, 1), 256, 0, stream>>>(
        h1bf, w2t, BDIM * NTOK, CDIM, 1536, 0, 0, 0, CDIM / 128,
        nullptr, b2, nullptr, y, out);
}